// Round 9
// baseline (386.926 us; speedup 1.0000x reference)
//
#include <hip/hip_runtime.h>
#include <hip/hip_bf16.h>

// MSACMixer: B=8, S=4096, D=1024
// out = ((softmax(x@wg^T) . {conv3,conv5,conv7}(val)) * sigmoid(gate)) @ w_down^T
// where [gate,val] = x @ w_up^T
//
// R8: gemm16 inner shape switched 16x16x32 -> 32x32x16 (mfma pipe 3378 -> 4096 FLOP/cyc,
//     m119). Wave tile 64x64 = 2x2 of 32x32, 8 MFMA/phase. Same LDS layout/swizzle
//     (reduces to ((lane&31)>>1)&3 for this pattern, <=2-way conflicts). Rest = R7.

#define MB 8
#define SS 4096
#define DD 1024
#define MM (MB * SS)   // 32768 rows
#define KD 1024
#define CR 32          // conv rows per block

typedef __attribute__((ext_vector_type(8))) short short8;
typedef __attribute__((ext_vector_type(4))) float f32x4;
typedef __attribute__((ext_vector_type(16))) float f32x16;

static __device__ __forceinline__ unsigned short f2bf(float f) {
    union { float f; unsigned u; } a; a.f = f;
    unsigned u = a.u;
    unsigned r = (u + 0x7FFFu + ((u >> 16) & 1u)) >> 16;   // RNE
    return (unsigned short)r;
}
static __device__ __forceinline__ float bf2f(unsigned short b) {
    union { unsigned u; float f; } a; a.u = ((unsigned)b) << 16;
    return a.f;
}

// ---------------------------------------------------------------- merged weight prep
__global__ void prep_misc(const float* __restrict__ w_up, const float* __restrict__ w_down,
                          const float* __restrict__ w3, const float* __restrict__ w5,
                          const float* __restrict__ w7,
                          ushort4* __restrict__ wub, ushort4* __restrict__ wdb,
                          float* __restrict__ wt) {
    const int n1 = 2048 * 1024 / 4, n2 = 1024 * 1024 / 4;
    int i = blockIdx.x * 256 + threadIdx.x;
    if (i < n1) {
        float4 v = ((const float4*)w_up)[i];
        ushort4 o; o.x = f2bf(v.x); o.y = f2bf(v.y); o.z = f2bf(v.z); o.w = f2bf(v.w);
        wub[i] = o;
    } else if (i < n1 + n2) {
        int j = i - n1;
        float4 v = ((const float4*)w_down)[j];
        ushort4 o; o.x = f2bf(v.x); o.y = f2bf(v.y); o.z = f2bf(v.z); o.w = f2bf(v.w);
        wdb[j] = o;
    } else if (i < n1 + n2 + DD) {
        int d = i - n1 - n2;
        #pragma unroll
        for (int j = 0; j < 3; j++) wt[j * DD + d] = w3[d * 3 + j];
        #pragma unroll
        for (int j = 0; j < 5; j++) wt[(3 + j) * DD + d] = w5[d * 5 + j];
        #pragma unroll
        for (int j = 0; j < 7; j++) wt[(8 + j) * DD + d] = w7[d * 7 + j];
    }
}

// ---------------------------------------------------------------- softmax gate weights + x cvt
__global__ void scale_cvt(const float* __restrict__ x, const float* __restrict__ wg,
                          unsigned short* __restrict__ xb, float* __restrict__ sw, int M) {
    int gw = (int)((blockIdx.x * (size_t)blockDim.x + threadIdx.x) >> 6);
    int lane = threadIdx.x & 63;
    if (gw >= M) return;
    const float* xr = x + (size_t)gw * DD + lane * 16;
    float4 xv[4];
    #pragma unroll
    for (int q = 0; q < 4; q++) xv[q] = ((const float4*)xr)[q];

    float s0 = 0.f, s1 = 0.f, s2 = 0.f;
    #pragma unroll
    for (int q = 0; q < 4; q++) {
        float4 w0 = ((const float4*)(wg + lane * 16))[q];
        float4 w1 = ((const float4*)(wg + DD + lane * 16))[q];
        float4 w2 = ((const float4*)(wg + 2 * DD + lane * 16))[q];
        s0 += xv[q].x*w0.x + xv[q].y*w0.y + xv[q].z*w0.z + xv[q].w*w0.w;
        s1 += xv[q].x*w1.x + xv[q].y*w1.y + xv[q].z*w1.z + xv[q].w*w1.w;
        s2 += xv[q].x*w2.x + xv[q].y*w2.y + xv[q].z*w2.z + xv[q].w*w2.w;
    }

    short8 ob[2];
    #pragma unroll
    for (int q = 0; q < 4; q++) {
        ob[q >> 1][(q & 1) * 4 + 0] = (short)f2bf(xv[q].x);
        ob[q >> 1][(q & 1) * 4 + 1] = (short)f2bf(xv[q].y);
        ob[q >> 1][(q & 1) * 4 + 2] = (short)f2bf(xv[q].z);
        ob[q >> 1][(q & 1) * 4 + 3] = (short)f2bf(xv[q].w);
    }
    *(short8*)(xb + (size_t)gw * DD + lane * 16) = ob[0];
    *(short8*)(xb + (size_t)gw * DD + lane * 16 + 8) = ob[1];

    #pragma unroll
    for (int off = 32; off >= 1; off >>= 1) {
        s0 += __shfl_xor(s0, off);
        s1 += __shfl_xor(s1, off);
        s2 += __shfl_xor(s2, off);
    }
    if (lane == 0) {
        float mx = fmaxf(s0, fmaxf(s1, s2));
        float e0 = expf(s0 - mx), e1 = expf(s1 - mx), e2 = expf(s2 - mx);
        float inv = 1.f / (e0 + e1 + e2);
        sw[(size_t)gw * 3 + 0] = e0 * inv;
        sw[(size_t)gw * 3 + 1] = e1 * inv;
        sw[(size_t)gw * 3 + 2] = e2 * inv;
    }
}

// ---------------------------------------------------------------- 16-wave 256^2 GEMM, 32x32x16
template <int EPI, int NBN>
__global__ __launch_bounds__(1024, 4) void gemm16(
    const unsigned short* __restrict__ A,   // [M,1024]
    const unsigned short* __restrict__ W,   // [N,1024]
    unsigned short* __restrict__ og,
    unsigned short* __restrict__ ov,
    float* __restrict__ of)
{
    __shared__ __align__(16) char lds[131072];
    const int tid = threadIdx.x;
    const int wid = tid >> 6, lane = tid & 63;
    const int l31 = lane & 31, g2 = lane >> 5;
    const int wr = wid >> 2, wc = wid & 3;

    const int flat = blockIdx.x + gridDim.x * blockIdx.y;
    const int k8 = flat & 7, j = flat >> 3;
    const int bn = j % NBN;
    const int bm = j / NBN + k8 * 16;

    const unsigned short* Ablk = A + (size_t)bm * 256 * KD;
    const unsigned short* Wblk = W + (size_t)bn * 256 * KD;

    const int r0 = tid >> 2;
    const int cch8 = (((tid & 3) ^ ((r0 >> 1) & 3)) << 3);
    const int dst0 = tid * 16;

    // 32x32x16 frag reads: lane -> row l31 (+mi*32), k-chunk (kk*2 + g2), XOR-swizzled.
    const int swz32 = (l31 >> 1) & 3;
    int aoff[2][2], boff[2][2];
    #pragma unroll
    for (int mi = 0; mi < 2; mi++)
        #pragma unroll
        for (int kk = 0; kk < 2; kk++) {
            aoff[mi][kk] = (wr * 64 + mi * 32 + l31) * 64 + (((kk * 2 + g2) ^ swz32) << 4);
            boff[mi][kk] = (wc * 64 + mi * 32 + l31) * 64 + (((kk * 2 + g2) ^ swz32) << 4);
        }

    f32x16 acc[2][2];
    #pragma unroll
    for (int m = 0; m < 2; m++)
        #pragma unroll
        for (int n = 0; n < 2; n++) acc[m][n] = (f32x16)0.f;

#define LDSA(r) (lds + (r) * 16384)
#define LDSB(r) (lds + 65536 + (r) * 16384)
#define STAGE1(gp, lb) __builtin_amdgcn_global_load_lds( \
        (const __attribute__((address_space(1))) void*)((gp) + (size_t)r0 * KD + cch8), \
        (__attribute__((address_space(3))) void*)((lb) + dst0), 16, 0, 0)

    STAGE1(Ablk +  0, LDSA(0)); STAGE1(Wblk +  0, LDSB(0));
    STAGE1(Ablk + 32, LDSA(1)); STAGE1(Wblk + 32, LDSB(1));
    STAGE1(Ablk + 64, LDSA(2)); STAGE1(Wblk + 64, LDSB(2));
    asm volatile("s_waitcnt vmcnt(4)" ::: "memory");
    __builtin_amdgcn_s_barrier();

#define PHASE(q, soff) do { \
    const char* ar = LDSA(q); const char* br = LDSB(q); \
    short8 a00 = *(const short8*)(ar + aoff[0][0]); \
    short8 a01 = *(const short8*)(ar + aoff[0][1]); \
    short8 a10 = *(const short8*)(ar + aoff[1][0]); \
    short8 a11 = *(const short8*)(ar + aoff[1][1]); \
    short8 b00 = *(const short8*)(br + boff[0][0]); \
    short8 b01 = *(const short8*)(br + boff[0][1]); \
    short8 b10 = *(const short8*)(br + boff[1][0]); \
    short8 b11 = *(const short8*)(br + boff[1][1]); \
    STAGE1(Ablk + (soff), LDSA(((q) + 3) & 3)); \
    STAGE1(Wblk + (soff), LDSB(((q) + 3) & 3)); \
    __builtin_amdgcn_s_setprio(1); \
    acc[0][0] = __builtin_amdgcn_mfma_f32_32x32x16_bf16(a00, b00, acc[0][0], 0, 0, 0); \
    acc[0][1] = __builtin_amdgcn_mfma_f32_32x32x16_bf16(a00, b10, acc[0][1], 0, 0, 0); \
    acc[1][0] = __builtin_amdgcn_mfma_f32_32x32x16_bf16(a10, b00, acc[1][0], 0, 0, 0); \
    acc[1][1] = __builtin_amdgcn_mfma_f32_32x32x16_bf16(a10, b10, acc[1][1], 0, 0, 0); \
    acc[0][0] = __builtin_amdgcn_mfma_f32_32x32x16_bf16(a01, b01, acc[0][0], 0, 0, 0); \
    acc[0][1] = __builtin_amdgcn_mfma_f32_32x32x16_bf16(a01, b11, acc[0][1], 0, 0, 0); \
    acc[1][0] = __builtin_amdgcn_mfma_f32_32x32x16_bf16(a11, b01, acc[1][0], 0, 0, 0); \
    acc[1][1] = __builtin_amdgcn_mfma_f32_32x32x16_bf16(a11, b11, acc[1][1], 0, 0, 0); \
    __builtin_amdgcn_s_setprio(0); \
    asm volatile("s_waitcnt vmcnt(4)" ::: "memory"); \
    __builtin_amdgcn_s_barrier(); \
  } while (0)

    #pragma unroll 1
    for (int it = 0; it < 8; ++it) {
        const int p0 = it * 4;
        const int g0 = (p0 + 3 < 31 ? p0 + 3 : 31) * 32;
        const int g1 = (p0 + 4 < 31 ? p0 + 4 : 31) * 32;
        const int gA = (p0 + 5 < 31 ? p0 + 5 : 31) * 32;
        const int gB = (p0 + 6 < 31 ? p0 + 6 : 31) * 32;
        PHASE(0, g0);
        PHASE(1, g1);
        PHASE(2, gA);
        PHASE(3, gB);
    }
    asm volatile("s_waitcnt vmcnt(0)" ::: "memory");

    // C/D (32x32): col = lane&31, row = (reg&3) + 8*(reg>>2) + 4*(lane>>5)   [m74/m101]
    const int grow0 = bm * 256 + wr * 64;
    const int gcol0 = bn * 256 + wc * 64;
    if (EPI == 0) {
        #pragma unroll
        for (int mi = 0; mi < 2; mi++) {
            #pragma unroll
            for (int ni = 0; ni < 2; ni++) {
                int gcol = gcol0 + ni * 32 + l31;
                bool isgate = gcol < 1024;          // uniform per block
                unsigned short* dst = isgate ? og : ov;
                int cc = isgate ? gcol : gcol - 1024;
                #pragma unroll
                for (int r = 0; r < 16; r++) {
                    int grow = grow0 + mi * 32 + (r & 3) + 8 * (r >> 2) + 4 * g2;
                    float v = acc[mi][ni][r];
                    float o = isgate ? (1.f / (1.f + __expf(-v))) : v;
                    dst[(size_t)grow * 1024 + cc] = f2bf(o);
                }
            }
        }
    } else {
        #pragma unroll
        for (int mi = 0; mi < 2; mi++) {
            #pragma unroll
            for (int ni = 0; ni < 2; ni++) {
                int gcol = gcol0 + ni * 32 + l31;
                #pragma unroll
                for (int r = 0; r < 16; r++) {
                    int grow = grow0 + mi * 32 + (r & 3) + 8 * (r >> 2) + 4 * g2;
                    of[(size_t)grow * 1024 + gcol] = acc[mi][ni][r];
                }
            }
        }
    }
#undef PHASE
#undef STAGE1
#undef LDSA
#undef LDSB
}

// ---------------------------------------------------------------- conv + softmax-mix + gate (R7)
__global__ __launch_bounds__(256) void conv_mix(
    const unsigned short* __restrict__ val,
    unsigned short* __restrict__ ga,      // gate in / A2 out (in place)
    const float* __restrict__ sw,
    const float* __restrict__ wt)         // transposed taps [15][DD]
{
    __shared__ unsigned short vlds[(CR + 6) * DD];   // 76 KB
    const int tid = threadIdx.x;
    const size_t r0 = (size_t)blockIdx.x * CR;
    const int sbase = (int)(r0 & (SS - 1));

    for (int idx = tid; idx < (CR + 6) * (DD / 8); idx += 256) {
        const int row = idx >> 7;
        const int chs = idx & 127;
        short8 v;
        if (sbase - 6 + row >= 0)
            v = *(const short8*)(val + (r0 - 6 + row) * (size_t)DD + chs * 8);
        else {
            #pragma unroll
            for (int i = 0; i < 8; i++) v[i] = 0;
        }
        *(short8*)(&vlds[row * DD + chs * 8]) = v;
    }
    __syncthreads();

    const int ch = tid & 127;
    const int rg = tid >> 7;
    const int d0 = ch * 8;
    const int k0 = rg * 16;

    float fw[15][8];
    #pragma unroll
    for (int j = 0; j < 15; j++) {
        float4 a = *(const float4*)(wt + j * DD + d0);
        float4 b = *(const float4*)(wt + j * DD + d0 + 4);
        fw[j][0] = a.x; fw[j][1] = a.y; fw[j][2] = a.z; fw[j][3] = a.w;
        fw[j][4] = b.x; fw[j][5] = b.y; fw[j][6] = b.z; fw[j][7] = b.w;
    }

    float fwin[7][8];
    #pragma unroll
    for (int jj = 0; jj < 6; jj++) {
        short8 v = *(const short8*)(&vlds[(k0 + jj) * DD + d0]);
        #pragma unroll
        for (int i = 0; i < 8; i++) fwin[jj][i] = bf2f((unsigned short)v[i]);
    }

    #pragma unroll
    for (int k = 0; k < 16; k++) {
        {
            short8 v = *(const short8*)(&vlds[(k0 + k + 6) * DD + d0]);
            #pragma unroll
            for (int i = 0; i < 8; i++) fwin[(k + 6) % 7][i] = bf2f((unsigned short)v[i]);
        }
        const size_t m = r0 + k0 + k;
        const float s0 = sw[m * 3 + 0], s1 = sw[m * 3 + 1], s2 = sw[m * 3 + 2];
        short8 g = *(const short8*)(ga + m * DD + d0);
        short8 o;
        #pragma unroll
        for (int i = 0; i < 8; i++) {
            float c7v = 0.f, c5v = 0.f, c3v = 0.f;
            #pragma unroll
            for (int t = 0; t < 7; t++) c7v += fwin[(k + t) % 7][i] * fw[8 + t][i];
            #pragma unroll
            for (int t = 0; t < 5; t++) c5v += fwin[(k + t + 2) % 7][i] * fw[3 + t][i];
            #pragma unroll
            for (int t = 0; t < 3; t++) c3v += fwin[(k + t + 4) % 7][i] * fw[t][i];
            float fused = s0 * c3v + s1 * c5v + s2 * c7v;
            o[i] = (short)f2bf(fused * bf2f((unsigned short)g[i]));
        }
        *(short8*)(ga + m * DD + d0) = o;
    }
}

// ---------------------------------------------------------------- launch
extern "C" void kernel_launch(void* const* d_in, const int* in_sizes, int n_in,
                              void* d_out, int out_size, void* d_ws, size_t ws_size,
                              hipStream_t stream) {
    const float* x      = (const float*)d_in[0];
    const float* w_up   = (const float*)d_in[1];
    const float* w_down = (const float*)d_in[2];
    const float* w_gate = (const float*)d_in[3];
    const float* w3     = (const float*)d_in[4];
    const float* w5     = (const float*)d_in[5];
    const float* w7     = (const float*)d_in[6];
    float* out = (float*)d_out;

    char* ws = (char*)d_ws;
    const size_t NX = (size_t)MM * DD;
    unsigned short* xb   = (unsigned short*)ws;                               // 64 MiB
    unsigned short* wub  = (unsigned short*)(ws + NX * 2);                    // 4 MiB
    unsigned short* wdb  = (unsigned short*)(ws + NX * 2 + 4194304);          // 2 MiB
    unsigned short* gate = (unsigned short*)(ws + NX * 2 + 6291456);          // 64 MiB (becomes A2)
    unsigned short* valb = (unsigned short*)(ws + NX * 2 + 6291456 + NX * 2); // 64 MiB
    float*          sw   = (float*)(ws + NX * 2 + 6291456 + NX * 4);          // 384 KiB
    float*          wt   = (float*)(ws + NX * 2 + 6291456 + NX * 4 + 393216); // 60 KiB

    prep_misc<<<(2048*1024/4 + 1024*1024/4 + DD + 255) / 256, 256, 0, stream>>>(
        w_up, w_down, w3, w5, w7, (ushort4*)wub, (ushort4*)wdb, wt);
    scale_cvt<<<MM / 4, 256, 0, stream>>>(x, w_gate, xb, sw, MM);
    gemm16<0, 8><<<dim3(MM / 256, 2048 / 256), 1024, 0, stream>>>(xb, wub, gate, valb, nullptr);
    conv_mix<<<MM / CR, 256, 0, stream>>>(valb, gate, sw, wt);
    gemm16<1, 4><<<dim3(MM / 256, 1024 / 256), 1024, 0, stream>>>(gate, wdb, nullptr, nullptr, out);
    (void)in_sizes; (void)n_in; (void)out_size; (void)ws_size;
}

// Round 10
// 353.135 us; speedup vs baseline: 1.0957x; 1.0957x over previous
//
#include <hip/hip_runtime.h>
#include <hip/hip_bf16.h>

// MSACMixer: B=8, S=4096, D=1024
// out = ((softmax(x@wg^T) . {conv3,conv5,conv7}(val)) * sigmoid(gate)) @ w_down^T
// where [gate,val] = x @ w_up^T
//
// R9: revert GEMM to R7's 16x16x32 (R8's 32x32 reintroduced bank conflicts: the XOR
//     swizzle is read-pattern-specific). Single tweak: STAGE issued BEFORE ds_reads
//     in each phase (T3 recipe). conv_mix/scale_cvt/prep unchanged from R7.

#define MB 8
#define SS 4096
#define DD 1024
#define MM (MB * SS)   // 32768 rows
#define KD 1024
#define CR 32          // conv rows per block

typedef __attribute__((ext_vector_type(8))) short short8;
typedef __attribute__((ext_vector_type(4))) float f32x4;

static __device__ __forceinline__ unsigned short f2bf(float f) {
    union { float f; unsigned u; } a; a.f = f;
    unsigned u = a.u;
    unsigned r = (u + 0x7FFFu + ((u >> 16) & 1u)) >> 16;   // RNE
    return (unsigned short)r;
}
static __device__ __forceinline__ float bf2f(unsigned short b) {
    union { unsigned u; float f; } a; a.u = ((unsigned)b) << 16;
    return a.f;
}

// ---------------------------------------------------------------- merged weight prep
__global__ void prep_misc(const float* __restrict__ w_up, const float* __restrict__ w_down,
                          const float* __restrict__ w3, const float* __restrict__ w5,
                          const float* __restrict__ w7,
                          ushort4* __restrict__ wub, ushort4* __restrict__ wdb,
                          float* __restrict__ wt) {
    const int n1 = 2048 * 1024 / 4, n2 = 1024 * 1024 / 4;
    int i = blockIdx.x * 256 + threadIdx.x;
    if (i < n1) {
        float4 v = ((const float4*)w_up)[i];
        ushort4 o; o.x = f2bf(v.x); o.y = f2bf(v.y); o.z = f2bf(v.z); o.w = f2bf(v.w);
        wub[i] = o;
    } else if (i < n1 + n2) {
        int j = i - n1;
        float4 v = ((const float4*)w_down)[j];
        ushort4 o; o.x = f2bf(v.x); o.y = f2bf(v.y); o.z = f2bf(v.z); o.w = f2bf(v.w);
        wdb[j] = o;
    } else if (i < n1 + n2 + DD) {
        int d = i - n1 - n2;
        #pragma unroll
        for (int j = 0; j < 3; j++) wt[j * DD + d] = w3[d * 3 + j];
        #pragma unroll
        for (int j = 0; j < 5; j++) wt[(3 + j) * DD + d] = w5[d * 5 + j];
        #pragma unroll
        for (int j = 0; j < 7; j++) wt[(8 + j) * DD + d] = w7[d * 7 + j];
    }
}

// ---------------------------------------------------------------- softmax gate weights + x cvt
__global__ void scale_cvt(const float* __restrict__ x, const float* __restrict__ wg,
                          unsigned short* __restrict__ xb, float* __restrict__ sw, int M) {
    int gw = (int)((blockIdx.x * (size_t)blockDim.x + threadIdx.x) >> 6);
    int lane = threadIdx.x & 63;
    if (gw >= M) return;
    const float* xr = x + (size_t)gw * DD + lane * 16;
    float4 xv[4];
    #pragma unroll
    for (int q = 0; q < 4; q++) xv[q] = ((const float4*)xr)[q];

    float s0 = 0.f, s1 = 0.f, s2 = 0.f;
    #pragma unroll
    for (int q = 0; q < 4; q++) {
        float4 w0 = ((const float4*)(wg + lane * 16))[q];
        float4 w1 = ((const float4*)(wg + DD + lane * 16))[q];
        float4 w2 = ((const float4*)(wg + 2 * DD + lane * 16))[q];
        s0 += xv[q].x*w0.x + xv[q].y*w0.y + xv[q].z*w0.z + xv[q].w*w0.w;
        s1 += xv[q].x*w1.x + xv[q].y*w1.y + xv[q].z*w1.z + xv[q].w*w1.w;
        s2 += xv[q].x*w2.x + xv[q].y*w2.y + xv[q].z*w2.z + xv[q].w*w2.w;
    }

    short8 ob[2];
    #pragma unroll
    for (int q = 0; q < 4; q++) {
        ob[q >> 1][(q & 1) * 4 + 0] = (short)f2bf(xv[q].x);
        ob[q >> 1][(q & 1) * 4 + 1] = (short)f2bf(xv[q].y);
        ob[q >> 1][(q & 1) * 4 + 2] = (short)f2bf(xv[q].z);
        ob[q >> 1][(q & 1) * 4 + 3] = (short)f2bf(xv[q].w);
    }
    *(short8*)(xb + (size_t)gw * DD + lane * 16) = ob[0];
    *(short8*)(xb + (size_t)gw * DD + lane * 16 + 8) = ob[1];

    #pragma unroll
    for (int off = 32; off >= 1; off >>= 1) {
        s0 += __shfl_xor(s0, off);
        s1 += __shfl_xor(s1, off);
        s2 += __shfl_xor(s2, off);
    }
    if (lane == 0) {
        float mx = fmaxf(s0, fmaxf(s1, s2));
        float e0 = expf(s0 - mx), e1 = expf(s1 - mx), e2 = expf(s2 - mx);
        float inv = 1.f / (e0 + e1 + e2);
        sw[(size_t)gw * 3 + 0] = e0 * inv;
        sw[(size_t)gw * 3 + 1] = e1 * inv;
        sw[(size_t)gw * 3 + 2] = e2 * inv;
    }
}

// ---------------------------------------------------------------- 16-wave 256^2 GEMM, 16x16x32
template <int EPI, int NBN>
__global__ __launch_bounds__(1024, 4) void gemm16(
    const unsigned short* __restrict__ A,   // [M,1024]
    const unsigned short* __restrict__ W,   // [N,1024]
    unsigned short* __restrict__ og,
    unsigned short* __restrict__ ov,
    float* __restrict__ of)
{
    __shared__ __align__(16) char lds[131072];
    const int tid = threadIdx.x;
    const int wid = tid >> 6, lane = tid & 63;
    const int l15 = lane & 15, l4 = lane >> 4;
    const int wr = wid >> 2, wc = wid & 3;

    const int flat = blockIdx.x + gridDim.x * blockIdx.y;
    const int k8 = flat & 7, j = flat >> 3;
    const int bn = j % NBN;
    const int bm = j / NBN + k8 * 16;

    const unsigned short* Ablk = A + (size_t)bm * 256 * KD;
    const unsigned short* Wblk = W + (size_t)bn * 256 * KD;

    const int r0 = tid >> 2;
    const int cch8 = (((tid & 3) ^ ((r0 >> 1) & 3)) << 3);
    const int dst0 = tid * 16;

    const int swz = ((l15 >> 1) & 3) << 4;
    const int aoff0 = (wr * 64 + l15) * 64 + ((l4 * 16) ^ swz);
    const int boff0 = (wc * 64 + l15) * 64 + ((l4 * 16) ^ swz);

    f32x4 acc[4][4];
    #pragma unroll
    for (int m = 0; m < 4; m++)
        #pragma unroll
        for (int n = 0; n < 4; n++) acc[m][n] = (f32x4)0.f;

#define LDSA(r) (lds + (r) * 16384)
#define LDSB(r) (lds + 65536 + (r) * 16384)
#define STAGE1(gp, lb) __builtin_amdgcn_global_load_lds( \
        (const __attribute__((address_space(1))) void*)((gp) + (size_t)r0 * KD + cch8), \
        (__attribute__((address_space(3))) void*)((lb) + dst0), 16, 0, 0)

    STAGE1(Ablk +  0, LDSA(0)); STAGE1(Wblk +  0, LDSB(0));
    STAGE1(Ablk + 32, LDSA(1)); STAGE1(Wblk + 32, LDSB(1));
    STAGE1(Ablk + 64, LDSA(2)); STAGE1(Wblk + 64, LDSB(2));
    asm volatile("s_waitcnt vmcnt(4)" ::: "memory");
    __builtin_amdgcn_s_barrier();

// phase: STAGE first (T3 recipe — DMA starts under the LDS-read skew), then ds_reads,
// MFMA, vmcnt(4), one barrier. Stage target region (q+3)&3 was last read at q-1 and is
// protected by that phase's barrier, so stage position within phase q is free.
#define PHASE(q, soff) do { \
    STAGE1(Ablk + (soff), LDSA(((q) + 3) & 3)); \
    STAGE1(Wblk + (soff), LDSB(((q) + 3) & 3)); \
    const char* ar = LDSA(q); const char* br = LDSB(q); \
    short8 af0 = *(const short8*)(ar + aoff0); \
    short8 af1 = *(const short8*)(ar + aoff0 + 1024); \
    short8 af2 = *(const short8*)(ar + aoff0 + 2048); \
    short8 af3 = *(const short8*)(ar + aoff0 + 3072); \
    short8 bf0 = *(const short8*)(br + boff0); \
    short8 bf1 = *(const short8*)(br + boff0 + 1024); \
    short8 bf2 = *(const short8*)(br + boff0 + 2048); \
    short8 bf3 = *(const short8*)(br + boff0 + 3072); \
    __builtin_amdgcn_s_setprio(1); \
    acc[0][0] = __builtin_amdgcn_mfma_f32_16x16x32_bf16(af0, bf0, acc[0][0], 0, 0, 0); \
    acc[0][1] = __builtin_amdgcn_mfma_f32_16x16x32_bf16(af0, bf1, acc[0][1], 0, 0, 0); \
    acc[0][2] = __builtin_amdgcn_mfma_f32_16x16x32_bf16(af0, bf2, acc[0][2], 0, 0, 0); \
    acc[0][3] = __builtin_amdgcn_mfma_f32_16x16x32_bf16(af0, bf3, acc[0][3], 0, 0, 0); \
    acc[1][0] = __builtin_amdgcn_mfma_f32_16x16x32_bf16(af1, bf0, acc[1][0], 0, 0, 0); \
    acc[1][1] = __builtin_amdgcn_mfma_f32_16x16x32_bf16(af1, bf1, acc[1][1], 0, 0, 0); \
    acc[1][2] = __builtin_amdgcn_mfma_f32_16x16x32_bf16(af1, bf2, acc[1][2], 0, 0, 0); \
    acc[1][3] = __builtin_amdgcn_mfma_f32_16x16x32_bf16(af1, bf3, acc[1][3], 0, 0, 0); \
    acc[2][0] = __builtin_amdgcn_mfma_f32_16x16x32_bf16(af2, bf0, acc[2][0], 0, 0, 0); \
    acc[2][1] = __builtin_amdgcn_mfma_f32_16x16x32_bf16(af2, bf1, acc[2][1], 0, 0, 0); \
    acc[2][2] = __builtin_amdgcn_mfma_f32_16x16x32_bf16(af2, bf2, acc[2][2], 0, 0, 0); \
    acc[2][3] = __builtin_amdgcn_mfma_f32_16x16x32_bf16(af2, bf3, acc[2][3], 0, 0, 0); \
    acc[3][0] = __builtin_amdgcn_mfma_f32_16x16x32_bf16(af3, bf0, acc[3][0], 0, 0, 0); \
    acc[3][1] = __builtin_amdgcn_mfma_f32_16x16x32_bf16(af3, bf1, acc[3][1], 0, 0, 0); \
    acc[3][2] = __builtin_amdgcn_mfma_f32_16x16x32_bf16(af3, bf2, acc[3][2], 0, 0, 0); \
    acc[3][3] = __builtin_amdgcn_mfma_f32_16x16x32_bf16(af3, bf3, acc[3][3], 0, 0, 0); \
    __builtin_amdgcn_s_setprio(0); \
    asm volatile("s_waitcnt vmcnt(4)" ::: "memory"); \
    __builtin_amdgcn_s_barrier(); \
  } while (0)

    #pragma unroll 1
    for (int it = 0; it < 8; ++it) {
        const int p0 = it * 4;
        const int g0 = (p0 + 3 < 31 ? p0 + 3 : 31) * 32;
        const int g1 = (p0 + 4 < 31 ? p0 + 4 : 31) * 32;
        const int gA = (p0 + 5 < 31 ? p0 + 5 : 31) * 32;
        const int gB = (p0 + 6 < 31 ? p0 + 6 : 31) * 32;
        PHASE(0, g0);
        PHASE(1, g1);
        PHASE(2, gA);
        PHASE(3, gB);
    }
    asm volatile("s_waitcnt vmcnt(0)" ::: "memory");

    const int grow0 = bm * 256 + wr * 64;
    const int gcol0 = bn * 256 + wc * 64;
    if (EPI == 0) {
        #pragma unroll
        for (int m = 0; m < 4; m++) {
            #pragma unroll
            for (int n = 0; n < 4; n++) {
                int gcol = gcol0 + n * 16 + l15;
                bool isgate = gcol < 1024;
                unsigned short* dst = isgate ? og : ov;
                int cc = isgate ? gcol : gcol - 1024;
                #pragma unroll
                for (int r = 0; r < 4; r++) {
                    int grow = grow0 + m * 16 + l4 * 4 + r;
                    float v = acc[m][n][r];
                    float o = isgate ? (1.f / (1.f + __expf(-v))) : v;
                    dst[(size_t)grow * 1024 + cc] = f2bf(o);
                }
            }
        }
    } else {
        #pragma unroll
        for (int m = 0; m < 4; m++) {
            #pragma unroll
            for (int n = 0; n < 4; n++) {
                int gcol = gcol0 + n * 16 + l15;
                #pragma unroll
                for (int r = 0; r < 4; r++) {
                    int grow = grow0 + m * 16 + l4 * 4 + r;
                    of[(size_t)grow * 1024 + gcol] = acc[m][n][r];
                }
            }
        }
    }
#undef PHASE
#undef STAGE1
#undef LDSA
#undef LDSB
}

// ---------------------------------------------------------------- conv + softmax-mix + gate (R7)
__global__ __launch_bounds__(256) void conv_mix(
    const unsigned short* __restrict__ val,
    unsigned short* __restrict__ ga,      // gate in / A2 out (in place)
    const float* __restrict__ sw,
    const float* __restrict__ wt)         // transposed taps [15][DD]
{
    __shared__ unsigned short vlds[(CR + 6) * DD];   // 76 KB
    const int tid = threadIdx.x;
    const size_t r0 = (size_t)blockIdx.x * CR;
    const int sbase = (int)(r0 & (SS - 1));

    for (int idx = tid; idx < (CR + 6) * (DD / 8); idx += 256) {
        const int row = idx >> 7;
        const int chs = idx & 127;
        short8 v;
        if (sbase - 6 + row >= 0)
            v = *(const short8*)(val + (r0 - 6 + row) * (size_t)DD + chs * 8);
        else {
            #pragma unroll
            for (int i = 0; i < 8; i++) v[i] = 0;
        }
        *(short8*)(&vlds[row * DD + chs * 8]) = v;
    }
    __syncthreads();

    const int ch = tid & 127;
    const int rg = tid >> 7;
    const int d0 = ch * 8;
    const int k0 = rg * 16;

    float fw[15][8];
    #pragma unroll
    for (int j = 0; j < 15; j++) {
        float4 a = *(const float4*)(wt + j * DD + d0);
        float4 b = *(const float4*)(wt + j * DD + d0 + 4);
        fw[j][0] = a.x; fw[j][1] = a.y; fw[j][2] = a.z; fw[j][3] = a.w;
        fw[j][4] = b.x; fw[j][5] = b.y; fw[j][6] = b.z; fw[j][7] = b.w;
    }

    float fwin[7][8];
    #pragma unroll
    for (int jj = 0; jj < 6; jj++) {
        short8 v = *(const short8*)(&vlds[(k0 + jj) * DD + d0]);
        #pragma unroll
        for (int i = 0; i < 8; i++) fwin[jj][i] = bf2f((unsigned short)v[i]);
    }

    #pragma unroll
    for (int k = 0; k < 16; k++) {
        {
            short8 v = *(const short8*)(&vlds[(k0 + k + 6) * DD + d0]);
            #pragma unroll
            for (int i = 0; i < 8; i++) fwin[(k + 6) % 7][i] = bf2f((unsigned short)v[i]);
        }
        const size_t m = r0 + k0 + k;
        const float s0 = sw[m * 3 + 0], s1 = sw[m * 3 + 1], s2 = sw[m * 3 + 2];
        short8 g = *(const short8*)(ga + m * DD + d0);
        short8 o;
        #pragma unroll
        for (int i = 0; i < 8; i++) {
            float c7v = 0.f, c5v = 0.f, c3v = 0.f;
            #pragma unroll
            for (int t = 0; t < 7; t++) c7v += fwin[(k + t) % 7][i] * fw[8 + t][i];
            #pragma unroll
            for (int t = 0; t < 5; t++) c5v += fwin[(k + t + 2) % 7][i] * fw[3 + t][i];
            #pragma unroll
            for (int t = 0; t < 3; t++) c3v += fwin[(k + t + 4) % 7][i] * fw[t][i];
            float fused = s0 * c3v + s1 * c5v + s2 * c7v;
            o[i] = (short)f2bf(fused * bf2f((unsigned short)g[i]));
        }
        *(short8*)(ga + m * DD + d0) = o;
    }
}

// ---------------------------------------------------------------- launch
extern "C" void kernel_launch(void* const* d_in, const int* in_sizes, int n_in,
                              void* d_out, int out_size, void* d_ws, size_t ws_size,
                              hipStream_t stream) {
    const float* x      = (const float*)d_in[0];
    const float* w_up   = (const float*)d_in[1];
    const float* w_down = (const float*)d_in[2];
    const float* w_gate = (const float*)d_in[3];
    const float* w3     = (const float*)d_in[4];
    const float* w5     = (const float*)d_in[5];
    const float* w7     = (const float*)d_in[6];
    float* out = (float*)d_out;

    char* ws = (char*)d_ws;
    const size_t NX = (size_t)MM * DD;
    unsigned short* xb   = (unsigned short*)ws;                               // 64 MiB
    unsigned short* wub  = (unsigned short*)(ws + NX * 2);                    // 4 MiB
    unsigned short* wdb  = (unsigned short*)(ws + NX * 2 + 4194304);          // 2 MiB
    unsigned short* gate = (unsigned short*)(ws + NX * 2 + 6291456);          // 64 MiB (becomes A2)
    unsigned short* valb = (unsigned short*)(ws + NX * 2 + 6291456 + NX * 2); // 64 MiB
    float*          sw   = (float*)(ws + NX * 2 + 6291456 + NX * 4);          // 384 KiB
    float*          wt   = (float*)(ws + NX * 2 + 6291456 + NX * 4 + 393216); // 60 KiB

    prep_misc<<<(2048*1024/4 + 1024*1024/4 + DD + 255) / 256, 256, 0, stream>>>(
        w_up, w_down, w3, w5, w7, (ushort4*)wub, (ushort4*)wdb, wt);
    scale_cvt<<<MM / 4, 256, 0, stream>>>(x, w_gate, xb, sw, MM);
    gemm16<0, 8><<<dim3(MM / 256, 2048 / 256), 1024, 0, stream>>>(xb, wub, gate, valb, nullptr);
    conv_mix<<<MM / CR, 256, 0, stream>>>(valb, gate, sw, wt);
    gemm16<1, 4><<<dim3(MM / 256, 1024 / 256), 1024, 0, stream>>>(gate, wdb, nullptr, nullptr, out);
    (void)in_sizes; (void)n_in; (void)out_size; (void)ws_size;
}

// Round 11
// 351.906 us; speedup vs baseline: 1.0995x; 1.0035x over previous
//
#include <hip/hip_runtime.h>
#include <hip/hip_bf16.h>

// MSACMixer: B=8, S=4096, D=1024
// out = ((softmax(x@wg^T) . {conv3,conv5,conv7}(val)) * sigmoid(gate)) @ w_down^T
// where [gate,val] = x @ w_up^T
//
// R10: merge prep_misc into scale_cvt -> single prep_all dispatch (block-range split).
//      GEMM = R9 (16x16x32, 16-wave, 4-phase, stage-first, 0 conflicts, ~860 TF = m248
//      reference ceiling for K=1024). conv_mix = R7 LDS-staged. 4 dispatches total.

#define MB 8
#define SS 4096
#define DD 1024
#define MM (MB * SS)   // 32768 rows
#define KD 1024
#define CR 32          // conv rows per block

typedef __attribute__((ext_vector_type(8))) short short8;
typedef __attribute__((ext_vector_type(4))) float f32x4;

static __device__ __forceinline__ unsigned short f2bf(float f) {
    union { float f; unsigned u; } a; a.f = f;
    unsigned u = a.u;
    unsigned r = (u + 0x7FFFu + ((u >> 16) & 1u)) >> 16;   // RNE
    return (unsigned short)r;
}
static __device__ __forceinline__ float bf2f(unsigned short b) {
    union { unsigned u; float f; } a; a.u = ((unsigned)b) << 16;
    return a.f;
}

// ---------------------------------------------------------------- fused prep: scale+cvt / weights
// blocks [0, MM/4): one wave per x-row -> xb bf16 + sw softmax(x@wg^T)
// blocks [MM/4, ...): w_up/w_down cvt + conv-weight transpose
__global__ void prep_all(const float* __restrict__ x, const float* __restrict__ wg,
                         const float* __restrict__ w_up, const float* __restrict__ w_down,
                         const float* __restrict__ w3, const float* __restrict__ w5,
                         const float* __restrict__ w7,
                         unsigned short* __restrict__ xb, float* __restrict__ sw,
                         ushort4* __restrict__ wub, ushort4* __restrict__ wdb,
                         float* __restrict__ wt) {
    const int bid = blockIdx.x;
    if (bid < MM / 4) {
        int gw = (int)(((size_t)bid * 256 + threadIdx.x) >> 6);
        int lane = threadIdx.x & 63;
        const float* xr = x + (size_t)gw * DD + lane * 16;
        float4 xv[4];
        #pragma unroll
        for (int q = 0; q < 4; q++) xv[q] = ((const float4*)xr)[q];

        float s0 = 0.f, s1 = 0.f, s2 = 0.f;
        #pragma unroll
        for (int q = 0; q < 4; q++) {
            float4 w0 = ((const float4*)(wg + lane * 16))[q];
            float4 w1 = ((const float4*)(wg + DD + lane * 16))[q];
            float4 w2 = ((const float4*)(wg + 2 * DD + lane * 16))[q];
            s0 += xv[q].x*w0.x + xv[q].y*w0.y + xv[q].z*w0.z + xv[q].w*w0.w;
            s1 += xv[q].x*w1.x + xv[q].y*w1.y + xv[q].z*w1.z + xv[q].w*w1.w;
            s2 += xv[q].x*w2.x + xv[q].y*w2.y + xv[q].z*w2.z + xv[q].w*w2.w;
        }

        short8 ob[2];
        #pragma unroll
        for (int q = 0; q < 4; q++) {
            ob[q >> 1][(q & 1) * 4 + 0] = (short)f2bf(xv[q].x);
            ob[q >> 1][(q & 1) * 4 + 1] = (short)f2bf(xv[q].y);
            ob[q >> 1][(q & 1) * 4 + 2] = (short)f2bf(xv[q].z);
            ob[q >> 1][(q & 1) * 4 + 3] = (short)f2bf(xv[q].w);
        }
        *(short8*)(xb + (size_t)gw * DD + lane * 16) = ob[0];
        *(short8*)(xb + (size_t)gw * DD + lane * 16 + 8) = ob[1];

        #pragma unroll
        for (int off = 32; off >= 1; off >>= 1) {
            s0 += __shfl_xor(s0, off);
            s1 += __shfl_xor(s1, off);
            s2 += __shfl_xor(s2, off);
        }
        if (lane == 0) {
            float mx = fmaxf(s0, fmaxf(s1, s2));
            float e0 = expf(s0 - mx), e1 = expf(s1 - mx), e2 = expf(s2 - mx);
            float inv = 1.f / (e0 + e1 + e2);
            sw[(size_t)gw * 3 + 0] = e0 * inv;
            sw[(size_t)gw * 3 + 1] = e1 * inv;
            sw[(size_t)gw * 3 + 2] = e2 * inv;
        }
    } else {
        const int n1 = 2048 * 1024 / 4, n2 = 1024 * 1024 / 4;
        int i = (bid - MM / 4) * 256 + threadIdx.x;
        if (i < n1) {
            float4 v = ((const float4*)w_up)[i];
            ushort4 o; o.x = f2bf(v.x); o.y = f2bf(v.y); o.z = f2bf(v.z); o.w = f2bf(v.w);
            wub[i] = o;
        } else if (i < n1 + n2) {
            int jj = i - n1;
            float4 v = ((const float4*)w_down)[jj];
            ushort4 o; o.x = f2bf(v.x); o.y = f2bf(v.y); o.z = f2bf(v.z); o.w = f2bf(v.w);
            wdb[jj] = o;
        } else if (i < n1 + n2 + DD) {
            int d = i - n1 - n2;
            #pragma unroll
            for (int j = 0; j < 3; j++) wt[j * DD + d] = w3[d * 3 + j];
            #pragma unroll
            for (int j = 0; j < 5; j++) wt[(3 + j) * DD + d] = w5[d * 5 + j];
            #pragma unroll
            for (int j = 0; j < 7; j++) wt[(8 + j) * DD + d] = w7[d * 7 + j];
        }
    }
}

// ---------------------------------------------------------------- 16-wave 256^2 GEMM, 16x16x32 (R9)
template <int EPI, int NBN>
__global__ __launch_bounds__(1024, 4) void gemm16(
    const unsigned short* __restrict__ A,   // [M,1024]
    const unsigned short* __restrict__ W,   // [N,1024]
    unsigned short* __restrict__ og,
    unsigned short* __restrict__ ov,
    float* __restrict__ of)
{
    __shared__ __align__(16) char lds[131072];
    const int tid = threadIdx.x;
    const int wid = tid >> 6, lane = tid & 63;
    const int l15 = lane & 15, l4 = lane >> 4;
    const int wr = wid >> 2, wc = wid & 3;

    const int flat = blockIdx.x + gridDim.x * blockIdx.y;
    const int k8 = flat & 7, j = flat >> 3;
    const int bn = j % NBN;
    const int bm = j / NBN + k8 * 16;

    const unsigned short* Ablk = A + (size_t)bm * 256 * KD;
    const unsigned short* Wblk = W + (size_t)bn * 256 * KD;

    const int r0 = tid >> 2;
    const int cch8 = (((tid & 3) ^ ((r0 >> 1) & 3)) << 3);
    const int dst0 = tid * 16;

    const int swz = ((l15 >> 1) & 3) << 4;
    const int aoff0 = (wr * 64 + l15) * 64 + ((l4 * 16) ^ swz);
    const int boff0 = (wc * 64 + l15) * 64 + ((l4 * 16) ^ swz);

    f32x4 acc[4][4];
    #pragma unroll
    for (int m = 0; m < 4; m++)
        #pragma unroll
        for (int n = 0; n < 4; n++) acc[m][n] = (f32x4)0.f;

#define LDSA(r) (lds + (r) * 16384)
#define LDSB(r) (lds + 65536 + (r) * 16384)
#define STAGE1(gp, lb) __builtin_amdgcn_global_load_lds( \
        (const __attribute__((address_space(1))) void*)((gp) + (size_t)r0 * KD + cch8), \
        (__attribute__((address_space(3))) void*)((lb) + dst0), 16, 0, 0)

    STAGE1(Ablk +  0, LDSA(0)); STAGE1(Wblk +  0, LDSB(0));
    STAGE1(Ablk + 32, LDSA(1)); STAGE1(Wblk + 32, LDSB(1));
    STAGE1(Ablk + 64, LDSA(2)); STAGE1(Wblk + 64, LDSB(2));
    asm volatile("s_waitcnt vmcnt(4)" ::: "memory");
    __builtin_amdgcn_s_barrier();

#define PHASE(q, soff) do { \
    STAGE1(Ablk + (soff), LDSA(((q) + 3) & 3)); \
    STAGE1(Wblk + (soff), LDSB(((q) + 3) & 3)); \
    const char* ar = LDSA(q); const char* br = LDSB(q); \
    short8 af0 = *(const short8*)(ar + aoff0); \
    short8 af1 = *(const short8*)(ar + aoff0 + 1024); \
    short8 af2 = *(const short8*)(ar + aoff0 + 2048); \
    short8 af3 = *(const short8*)(ar + aoff0 + 3072); \
    short8 bf0 = *(const short8*)(br + boff0); \
    short8 bf1 = *(const short8*)(br + boff0 + 1024); \
    short8 bf2 = *(const short8*)(br + boff0 + 2048); \
    short8 bf3 = *(const short8*)(br + boff0 + 3072); \
    __builtin_amdgcn_s_setprio(1); \
    acc[0][0] = __builtin_amdgcn_mfma_f32_16x16x32_bf16(af0, bf0, acc[0][0], 0, 0, 0); \
    acc[0][1] = __builtin_amdgcn_mfma_f32_16x16x32_bf16(af0, bf1, acc[0][1], 0, 0, 0); \
    acc[0][2] = __builtin_amdgcn_mfma_f32_16x16x32_bf16(af0, bf2, acc[0][2], 0, 0, 0); \
    acc[0][3] = __builtin_amdgcn_mfma_f32_16x16x32_bf16(af0, bf3, acc[0][3], 0, 0, 0); \
    acc[1][0] = __builtin_amdgcn_mfma_f32_16x16x32_bf16(af1, bf0, acc[1][0], 0, 0, 0); \
    acc[1][1] = __builtin_amdgcn_mfma_f32_16x16x32_bf16(af1, bf1, acc[1][1], 0, 0, 0); \
    acc[1][2] = __builtin_amdgcn_mfma_f32_16x16x32_bf16(af1, bf2, acc[1][2], 0, 0, 0); \
    acc[1][3] = __builtin_amdgcn_mfma_f32_16x16x32_bf16(af1, bf3, acc[1][3], 0, 0, 0); \
    acc[2][0] = __builtin_amdgcn_mfma_f32_16x16x32_bf16(af2, bf0, acc[2][0], 0, 0, 0); \
    acc[2][1] = __builtin_amdgcn_mfma_f32_16x16x32_bf16(af2, bf1, acc[2][1], 0, 0, 0); \
    acc[2][2] = __builtin_amdgcn_mfma_f32_16x16x32_bf16(af2, bf2, acc[2][2], 0, 0, 0); \
    acc[2][3] = __builtin_amdgcn_mfma_f32_16x16x32_bf16(af2, bf3, acc[2][3], 0, 0, 0); \
    acc[3][0] = __builtin_amdgcn_mfma_f32_16x16x32_bf16(af3, bf0, acc[3][0], 0, 0, 0); \
    acc[3][1] = __builtin_amdgcn_mfma_f32_16x16x32_bf16(af3, bf1, acc[3][1], 0, 0, 0); \
    acc[3][2] = __builtin_amdgcn_mfma_f32_16x16x32_bf16(af3, bf2, acc[3][2], 0, 0, 0); \
    acc[3][3] = __builtin_amdgcn_mfma_f32_16x16x32_bf16(af3, bf3, acc[3][3], 0, 0, 0); \
    __builtin_amdgcn_s_setprio(0); \
    asm volatile("s_waitcnt vmcnt(4)" ::: "memory"); \
    __builtin_amdgcn_s_barrier(); \
  } while (0)

    #pragma unroll 1
    for (int it = 0; it < 8; ++it) {
        const int p0 = it * 4;
        const int g0 = (p0 + 3 < 31 ? p0 + 3 : 31) * 32;
        const int g1 = (p0 + 4 < 31 ? p0 + 4 : 31) * 32;
        const int gA = (p0 + 5 < 31 ? p0 + 5 : 31) * 32;
        const int gB = (p0 + 6 < 31 ? p0 + 6 : 31) * 32;
        PHASE(0, g0);
        PHASE(1, g1);
        PHASE(2, gA);
        PHASE(3, gB);
    }
    asm volatile("s_waitcnt vmcnt(0)" ::: "memory");

    const int grow0 = bm * 256 + wr * 64;
    const int gcol0 = bn * 256 + wc * 64;
    if (EPI == 0) {
        #pragma unroll
        for (int m = 0; m < 4; m++) {
            #pragma unroll
            for (int n = 0; n < 4; n++) {
                int gcol = gcol0 + n * 16 + l15;
                bool isgate = gcol < 1024;
                unsigned short* dst = isgate ? og : ov;
                int cc = isgate ? gcol : gcol - 1024;
                #pragma unroll
                for (int r = 0; r < 4; r++) {
                    int grow = grow0 + m * 16 + l4 * 4 + r;
                    float v = acc[m][n][r];
                    float o = isgate ? (1.f / (1.f + __expf(-v))) : v;
                    dst[(size_t)grow * 1024 + cc] = f2bf(o);
                }
            }
        }
    } else {
        #pragma unroll
        for (int m = 0; m < 4; m++) {
            #pragma unroll
            for (int n = 0; n < 4; n++) {
                int gcol = gcol0 + n * 16 + l15;
                #pragma unroll
                for (int r = 0; r < 4; r++) {
                    int grow = grow0 + m * 16 + l4 * 4 + r;
                    of[(size_t)grow * 1024 + gcol] = acc[m][n][r];
                }
            }
        }
    }
#undef PHASE
#undef STAGE1
#undef LDSA
#undef LDSB
}

// ---------------------------------------------------------------- conv + softmax-mix + gate (R7)
__global__ __launch_bounds__(256) void conv_mix(
    const unsigned short* __restrict__ val,
    unsigned short* __restrict__ ga,      // gate in / A2 out (in place)
    const float* __restrict__ sw,
    const float* __restrict__ wt)         // transposed taps [15][DD]
{
    __shared__ unsigned short vlds[(CR + 6) * DD];   // 76 KB
    const int tid = threadIdx.x;
    const size_t r0 = (size_t)blockIdx.x * CR;
    const int sbase = (int)(r0 & (SS - 1));

    for (int idx = tid; idx < (CR + 6) * (DD / 8); idx += 256) {
        const int row = idx >> 7;
        const int chs = idx & 127;
        short8 v;
        if (sbase - 6 + row >= 0)
            v = *(const short8*)(val + (r0 - 6 + row) * (size_t)DD + chs * 8);
        else {
            #pragma unroll
            for (int i = 0; i < 8; i++) v[i] = 0;
        }
        *(short8*)(&vlds[row * DD + chs * 8]) = v;
    }
    __syncthreads();

    const int ch = tid & 127;
    const int rg = tid >> 7;
    const int d0 = ch * 8;
    const int k0 = rg * 16;

    float fw[15][8];
    #pragma unroll
    for (int j = 0; j < 15; j++) {
        float4 a = *(const float4*)(wt + j * DD + d0);
        float4 b = *(const float4*)(wt + j * DD + d0 + 4);
        fw[j][0] = a.x; fw[j][1] = a.y; fw[j][2] = a.z; fw[j][3] = a.w;
        fw[j][4] = b.x; fw[j][5] = b.y; fw[j][6] = b.z; fw[j][7] = b.w;
    }

    float fwin[7][8];
    #pragma unroll
    for (int jj = 0; jj < 6; jj++) {
        short8 v = *(const short8*)(&vlds[(k0 + jj) * DD + d0]);
        #pragma unroll
        for (int i = 0; i < 8; i++) fwin[jj][i] = bf2f((unsigned short)v[i]);
    }

    #pragma unroll
    for (int k = 0; k < 16; k++) {
        {
            short8 v = *(const short8*)(&vlds[(k0 + k + 6) * DD + d0]);
            #pragma unroll
            for (int i = 0; i < 8; i++) fwin[(k + 6) % 7][i] = bf2f((unsigned short)v[i]);
        }
        const size_t m = r0 + k0 + k;
        const float s0 = sw[m * 3 + 0], s1 = sw[m * 3 + 1], s2 = sw[m * 3 + 2];
        short8 g = *(const short8*)(ga + m * DD + d0);
        short8 o;
        #pragma unroll
        for (int i = 0; i < 8; i++) {
            float c7v = 0.f, c5v = 0.f, c3v = 0.f;
            #pragma unroll
            for (int t = 0; t < 7; t++) c7v += fwin[(k + t) % 7][i] * fw[8 + t][i];
            #pragma unroll
            for (int t = 0; t < 5; t++) c5v += fwin[(k + t + 2) % 7][i] * fw[3 + t][i];
            #pragma unroll
            for (int t = 0; t < 3; t++) c3v += fwin[(k + t + 4) % 7][i] * fw[t][i];
            float fused = s0 * c3v + s1 * c5v + s2 * c7v;
            o[i] = (short)f2bf(fused * bf2f((unsigned short)g[i]));
        }
        *(short8*)(ga + m * DD + d0) = o;
    }
}

// ---------------------------------------------------------------- launch
extern "C" void kernel_launch(void* const* d_in, const int* in_sizes, int n_in,
                              void* d_out, int out_size, void* d_ws, size_t ws_size,
                              hipStream_t stream) {
    const float* x      = (const float*)d_in[0];
    const float* w_up   = (const float*)d_in[1];
    const float* w_down = (const float*)d_in[2];
    const float* w_gate = (const float*)d_in[3];
    const float* w3     = (const float*)d_in[4];
    const float* w5     = (const float*)d_in[5];
    const float* w7     = (const float*)d_in[6];
    float* out = (float*)d_out;

    char* ws = (char*)d_ws;
    const size_t NX = (size_t)MM * DD;
    unsigned short* xb   = (unsigned short*)ws;                               // 64 MiB
    unsigned short* wub  = (unsigned short*)(ws + NX * 2);                    // 4 MiB
    unsigned short* wdb  = (unsigned short*)(ws + NX * 2 + 4194304);          // 2 MiB
    unsigned short* gate = (unsigned short*)(ws + NX * 2 + 6291456);          // 64 MiB (becomes A2)
    unsigned short* valb = (unsigned short*)(ws + NX * 2 + 6291456 + NX * 2); // 64 MiB
    float*          sw   = (float*)(ws + NX * 2 + 6291456 + NX * 4);          // 384 KiB
    float*          wt   = (float*)(ws + NX * 2 + 6291456 + NX * 4 + 393216); // 60 KiB

    const int prep_blocks = MM / 4 + (2048 * 1024 / 4 + 1024 * 1024 / 4 + DD + 255) / 256;
    prep_all<<<prep_blocks, 256, 0, stream>>>(x, w_gate, w_up, w_down, w3, w5, w7,
                                              xb, sw, (ushort4*)wub, (ushort4*)wdb, wt);
    gemm16<0, 8><<<dim3(MM / 256, 2048 / 256), 1024, 0, stream>>>(xb, wub, gate, valb, nullptr);
    conv_mix<<<MM / CR, 256, 0, stream>>>(valb, gate, sw, wt);
    gemm16<1, 4><<<dim3(MM / 256, 1024 / 256), 1024, 0, stream>>>(gate, wdb, nullptr, nullptr, out);
    (void)in_sizes; (void)n_in; (void)out_size; (void)ws_size;
}